// Round 18
// baseline (601.609 us; speedup 1.0000x reference)
//
#include <hip/hip_runtime.h>
#include <hip/hip_fp16.h>
#include <math.h>
#include <string.h>

#define NN 50000
#define NE 400000

__device__ __forceinline__ void atomAddF(float* p, float v) { unsafeAtomicAdd(p, v); }
__device__ __forceinline__ double atomAddD(double* p, double v) { return unsafeAtomicAdd(p, v); }
__device__ __forceinline__ int atomAddI(int* p, int v) { return atomicAdd(p, v); }

typedef _Float16 h2v __attribute__((ext_vector_type(2)));

__device__ __forceinline__ float2 up2h(unsigned v) {
  __half2 h; memcpy(&h, &v, 4); return __half22float2(h);
}
__device__ __forceinline__ unsigned pk2h(float a, float b) {
  __half2 h = __floats2half2_rn(a, b);
  unsigned v; memcpy(&v, &h, 4); return v;
}
__device__ __forceinline__ void up8(uint4 u, float* f) {
  float2 a = up2h(u.x), b = up2h(u.y), c = up2h(u.z), d = up2h(u.w);
  f[0] = a.x; f[1] = a.y; f[2] = b.x; f[3] = b.y;
  f[4] = c.x; f[5] = c.y; f[6] = d.x; f[7] = d.y;
}
__device__ __forceinline__ uint4 pk8(const float* f) {
  uint4 u;
  u.x = pk2h(f[0], f[1]); u.y = pk2h(f[2], f[3]);
  u.z = pk2h(f[4], f[5]); u.w = pk2h(f[6], f[7]);
  return u;
}

#if __has_builtin(__builtin_amdgcn_fdot2)
__device__ __forceinline__ float dot2(unsigned a, unsigned b, float c) {
  return __builtin_amdgcn_fdot2(__builtin_bit_cast(h2v, a), __builtin_bit_cast(h2v, b), c, false);
}
#else
__device__ __forceinline__ float dot2(unsigned a, unsigned b, float c) {
  float2 fa = up2h(a), fb = up2h(b);
  return c + fa.x * fb.x + fa.y * fb.y;
}
#endif

// swizzle for half2-pair LDS tiles: keeps 4-row alignment (low 2 bits zero)
#define SW(kk) ((((kk) & 7)) << 2)

// ---------------- zero fill ----------------
__global__ __launch_bounds__(256) void k_zero(float4* __restrict__ p, int n4) {
  int i = blockIdx.x * 256 + threadIdx.x;
  int s = gridDim.x * 256;
  for (; i < n4; i += s) p[i] = make_float4(0.f, 0.f, 0.f, 0.f);
}

// ---------------- CSR build ----------------
__global__ __launch_bounds__(256) void k_deg(const int* __restrict__ dst, int* __restrict__ deg) {
  int i = blockIdx.x * 256 + threadIdx.x;
  if (i < NE) atomAddI(&deg[dst[i]], 1);
}

__global__ __launch_bounds__(1024) void k_scan(int* __restrict__ degcur,
    int* __restrict__ offs, double* __restrict__ stats) {
  __shared__ int wsum[16];
  int t = threadIdx.x;
  int lane = t & 63, w = t >> 6;
  if (t < 256) stats[t] = 0.0;
  int carry = 0;
  for (int base = 0; base < NN; base += 1024) {
    int i = base + t;
    int v = (i < NN) ? degcur[i] : 0;
    int x = v;
    #pragma unroll
    for (int off = 1; off < 64; off <<= 1) {
      int y = __shfl_up(x, off);
      if (lane >= off) x += y;
    }
    if (lane == 63) wsum[w] = x;
    __syncthreads();
    if (w == 0 && lane < 16) {
      int s = wsum[lane];
      #pragma unroll
      for (int off = 1; off < 16; off <<= 1) {
        int y = __shfl_up(s, off);
        if (lane >= off) s += y;
      }
      wsum[lane] = s;
    }
    __syncthreads();
    int wbase = (w > 0) ? wsum[w - 1] : 0;
    int total = wsum[15];
    int excl = carry + wbase + x - v;
    if (i < NN) { offs[i] = excl; degcur[i] = excl; }
    carry += total;
    __syncthreads();
  }
  if (t == 0) offs[NN] = carry;
}

__global__ __launch_bounds__(256) void k_scatter(const int* __restrict__ dst,
    const int* __restrict__ src, const float* __restrict__ e_feat,
    int* __restrict__ cursor,
    int* __restrict__ srcp, int* __restrict__ dstp, float* __restrict__ ef2) {
  int i = blockIdx.x * 256 + threadIdx.x;
  if (i < NE) {
    int d = dst[i];
    int p = atomAddI(&cursor[d], 1);
    srcp[p] = src[i];
    dstp[p] = d;
    ((float2*)ef2)[p] = ((const float2*)e_feat)[i];
  }
}

// ---------------- node GEMM, 256-row tile, 512 threads, half2-pair LDS + dot2 -------
// MODE==2 (layer 0): compute h = hf@emb_w + emb_b during staging, write h (fp32).
// MODE==1: h_new = h + relu(Ah16*sc + sh); write h back (fp32). GEMM uses fp16(h).
// Outputs: Ah16/Bh/Dh/Eh fp16.
template <int MODE>
__global__ __launch_bounds__(512) void k_node_gemm(float* __restrict__ h,
    const __half* __restrict__ Ah_in, const float* __restrict__ bnp,
    const float* __restrict__ hf, const float* __restrict__ ehw,
    const float* __restrict__ ehb,
    const float* __restrict__ w0, const float* __restrict__ w1,
    const float* __restrict__ w2, const float* __restrict__ w3,
    const float* __restrict__ b0, const float* __restrict__ b1,
    const float* __restrict__ b2, const float* __restrict__ b3,
    __half* __restrict__ Ah16, __half* __restrict__ Bh16,
    __half* __restrict__ Dh16, __half* __restrict__ Eh16) {
  __shared__ __align__(16) unsigned hsU[32 * 256];   // [kk][row ^ SW(kk)] half2, 32KB
  __shared__ __align__(16) unsigned wshU[32 * 64];   // [kk][col] half2, 8KB
  int t = threadIdx.x;
  int n0 = blockIdx.x * 256;
  #pragma unroll
  for (int i = 0; i < 8; ++i) {
    int f = (t + i * 512) * 4;
    int r = f >> 6;          // 0..255
    int k = f & 63;          // multiple of 4
    int n = n0 + r;
    float4 v = make_float4(0.f, 0.f, 0.f, 0.f);
    if (n < NN) {
      size_t idx = (size_t)n * 64 + k;
      if (MODE == 2) {
        const float* row = hf + (size_t)n * 6;
        v = *(const float4*)(ehb + k);
        #pragma unroll
        for (int q = 0; q < 6; ++q) {
          float x = row[q];
          float4 wv = *(const float4*)(ehw + q * 64 + k);
          v.x += x * wv.x; v.y += x * wv.y; v.z += x * wv.z; v.w += x * wv.w;
        }
        *(float4*)(h + idx) = v;
      } else {
        v = *(const float4*)(h + idx);
        if (MODE == 1) {
          uint2 au = *(const uint2*)(Ah_in + idx);
          float2 a01 = up2h(au.x), a23 = up2h(au.y);
          float4 sc4 = *(const float4*)(bnp + k);
          float4 sh4 = *(const float4*)(bnp + 64 + k);
          v.x += fmaxf(a01.x * sc4.x + sh4.x, 0.f);
          v.y += fmaxf(a01.y * sc4.y + sh4.y, 0.f);
          v.z += fmaxf(a23.x * sc4.z + sh4.z, 0.f);
          v.w += fmaxf(a23.y * sc4.w + sh4.w, 0.f);
          *(float4*)(h + idx) = v;
        }
      }
    }
    int kk0 = k >> 1;        // multiple of 2
    hsU[(kk0 + 0) * 256 + (r ^ SW(kk0 + 0))] = pk2h(v.x, v.y);
    hsU[(kk0 + 1) * 256 + (r ^ SW(kk0 + 1))] = pk2h(v.z, v.w);
  }
  int cg = t & 7, rg = t >> 3;   // rg 0..63 (4 rows each), cg 0..7 (8 cols)
  int cb = cg * 8;
  #pragma unroll 1
  for (int y = 0; y < 4; ++y) {
    const float* W = (y == 0) ? w0 : (y == 1) ? w1 : (y == 2) ? w2 : w3;
    const float* B = (y == 0) ? b0 : (y == 1) ? b1 : (y == 2) ? b2 : b3;
    __syncthreads();
    #pragma unroll
    for (int i = 0; i < 4; ++i) {
      int idx = t + i * 512;     // 0..2047
      int kk = idx >> 6, j = idx & 63;
      wshU[idx] = pk2h(W[(2 * kk) * 64 + j], W[(2 * kk + 1) * 64 + j]);
    }
    __syncthreads();
    float acc[4][8];
    #pragma unroll
    for (int r = 0; r < 4; ++r)
      #pragma unroll
      for (int j = 0; j < 8; ++j) acc[r][j] = 0.f;
    #pragma unroll 8
    for (int kk = 0; kk < 32; ++kk) {
      uint4 a4 = *(const uint4*)&hsU[kk * 256 + ((rg * 4) ^ SW(kk))];
      uint4 wA = *(const uint4*)&wshU[kk * 64 + cb];
      uint4 wB = *(const uint4*)&wshU[kk * 64 + cb + 4];
      unsigned av[4] = {a4.x, a4.y, a4.z, a4.w};
      unsigned wv[8] = {wA.x, wA.y, wA.z, wA.w, wB.x, wB.y, wB.z, wB.w};
      #pragma unroll
      for (int r = 0; r < 4; ++r)
        #pragma unroll
        for (int j = 0; j < 8; ++j) acc[r][j] = dot2(av[r], wv[j], acc[r][j]);
    }
    float4 bv0 = *(const float4*)(B + cb);
    float4 bv1 = *(const float4*)(B + cb + 4);
    float bv[8] = {bv0.x, bv0.y, bv0.z, bv0.w, bv1.x, bv1.y, bv1.z, bv1.w};
    __half* oh = (y == 0) ? Ah16 : (y == 1) ? Bh16 : (y == 2) ? Dh16 : Eh16;
    #pragma unroll
    for (int r = 0; r < 4; ++r) {
      int n = n0 + rg * 4 + r;
      if (n < NN) {
        float o[8];
        #pragma unroll
        for (int j = 0; j < 8; ++j) o[j] = acc[r][j] + bv[j];
        *(uint4*)(oh + (size_t)n * 64 + cb) = pk8(o);
      }
    }
  }
}

// ---------------- fused edge kernel, 256-row tile, 512 threads, half2-pair LDS ------
// MODE==1: e_new = e16 + relu(eh16_prev*sc+sh). MODE==2: compute e from raw CSR pairs
// ef2 + embedding (layer 0). EWRITE: persist e16.
// ehat = e@Cw + Cb + Dh16[srcp] + Eh16[dstp]; store fp16; ESTATS: e-BN stats.
template <int MODE, int ESTATS, int EWRITE>
__global__ __launch_bounds__(512) void k_edge_f(__half* __restrict__ e16,
    __half* __restrict__ eh16,
    const float* __restrict__ Cw, const float* __restrict__ Cb,
    const int* __restrict__ srcp, const int* __restrict__ dstp,
    const __half* __restrict__ Dh16, const __half* __restrict__ Eh16,
    const float* __restrict__ bnp, double* __restrict__ stats,
    const float* __restrict__ ef2, const float* __restrict__ ew,
    const float* __restrict__ eb) {
  __shared__ __align__(16) unsigned esU[32 * 256];   // [kk][row ^ SW(kk)] half2, 32KB
  __shared__ __align__(16) unsigned cwU[32 * 64];    // [kk][col] half2, 8KB
  int t = threadIdx.x;
  int e0 = blockIdx.x * 256;
  #pragma unroll
  for (int i = 0; i < 4; ++i) {
    int idx = t + i * 512;
    int kk = idx >> 6, j = idx & 63;
    cwU[idx] = pk2h(Cw[(2 * kk) * 64 + j], Cw[(2 * kk + 1) * 64 + j]);
  }
  #pragma unroll
  for (int i = 0; i < 4; ++i) {
    int f = (t + i * 512) * 8;
    int r = f >> 6;          // 0..255
    int k = f & 63;          // multiple of 8
    int row = e0 + r;
    uint4 raw = make_uint4(0u, 0u, 0u, 0u);
    if (row < NE) {
      size_t idx = (size_t)row * 64 + k;
      if (MODE == 2) {
        float2 rp = ((const float2*)ef2)[row];
        float r0 = 1.0f / rp.x;
        float r1 = 1.0f / rp.y;
        float4 bA = *(const float4*)(eb + k), bB = *(const float4*)(eb + k + 4);
        float4 waA = *(const float4*)(ew + k), waB = *(const float4*)(ew + k + 4);
        float4 wbA = *(const float4*)(ew + 64 + k), wbB = *(const float4*)(ew + 64 + k + 4);
        float v[8];
        v[0] = bA.x + r0 * waA.x + r1 * wbA.x;
        v[1] = bA.y + r0 * waA.y + r1 * wbA.y;
        v[2] = bA.z + r0 * waA.z + r1 * wbA.z;
        v[3] = bA.w + r0 * waA.w + r1 * wbA.w;
        v[4] = bB.x + r0 * waB.x + r1 * wbB.x;
        v[5] = bB.y + r0 * waB.y + r1 * wbB.y;
        v[6] = bB.z + r0 * waB.z + r1 * wbB.z;
        v[7] = bB.w + r0 * waB.w + r1 * wbB.w;
        raw = pk8(v);
        if (EWRITE) *(uint4*)(e16 + idx) = raw;
      } else {
        raw = *(const uint4*)(e16 + idx);
        if (MODE == 1) {
          float v[8], pp[8];
          up8(raw, v);
          up8(*(const uint4*)(eh16 + idx), pp);
          float4 scA = *(const float4*)(bnp + 128 + k);
          float4 scB = *(const float4*)(bnp + 128 + k + 4);
          float4 shA = *(const float4*)(bnp + 192 + k);
          float4 shB = *(const float4*)(bnp + 192 + k + 4);
          float sc[8] = {scA.x, scA.y, scA.z, scA.w, scB.x, scB.y, scB.z, scB.w};
          float sh[8] = {shA.x, shA.y, shA.z, shA.w, shB.x, shB.y, shB.z, shB.w};
          #pragma unroll
          for (int j = 0; j < 8; ++j) v[j] += fmaxf(pp[j] * sc[j] + sh[j], 0.f);
          raw = pk8(v);
          if (EWRITE) *(uint4*)(e16 + idx) = raw;
        }
      }
    }
    int kk0 = k >> 1;        // multiple of 4
    esU[(kk0 + 0) * 256 + (r ^ SW(kk0 + 0))] = raw.x;
    esU[(kk0 + 1) * 256 + (r ^ SW(kk0 + 1))] = raw.y;
    esU[(kk0 + 2) * 256 + (r ^ SW(kk0 + 2))] = raw.z;
    esU[(kk0 + 3) * 256 + (r ^ SW(kk0 + 3))] = raw.w;
  }
  __syncthreads();
  int cg = t & 7, rg = t >> 3;   // rg 0..63 (4 rows each)
  int cb = cg * 8;
  float acc[4][8];
  #pragma unroll
  for (int r = 0; r < 4; ++r)
    #pragma unroll
    for (int j = 0; j < 8; ++j) acc[r][j] = 0.f;
  #pragma unroll 8
  for (int kk = 0; kk < 32; ++kk) {
    uint4 a4 = *(const uint4*)&esU[kk * 256 + ((rg * 4) ^ SW(kk))];
    uint4 wA = *(const uint4*)&cwU[kk * 64 + cb];
    uint4 wB = *(const uint4*)&cwU[kk * 64 + cb + 4];
    unsigned av[4] = {a4.x, a4.y, a4.z, a4.w};
    unsigned wv[8] = {wA.x, wA.y, wA.z, wA.w, wB.x, wB.y, wB.z, wB.w};
    #pragma unroll
    for (int r = 0; r < 4; ++r)
      #pragma unroll
      for (int j = 0; j < 8; ++j) acc[r][j] = dot2(av[r], wv[j], acc[r][j]);
  }
  float4 cb0 = *(const float4*)(Cb + cb);
  float4 cb1 = *(const float4*)(Cb + cb + 4);
  float cbv[8] = {cb0.x, cb0.y, cb0.z, cb0.w, cb1.x, cb1.y, cb1.z, cb1.w};
  float psum[8], psq[8];
  #pragma unroll
  for (int j = 0; j < 8; ++j) { psum[j] = 0.f; psq[j] = 0.f; }
  #pragma unroll
  for (int r = 0; r < 4; ++r) {
    int p = e0 + rg * 4 + r;
    if (p < NE) {
      int sN = srcp[p], dN = dstp[p];
      float dd[8], qq[8];
      up8(*(const uint4*)(Dh16 + (size_t)sN * 64 + cb), dd);
      up8(*(const uint4*)(Eh16 + (size_t)dN * 64 + cb), qq);
      float ev[8];
      #pragma unroll
      for (int j = 0; j < 8; ++j) {
        float v = acc[r][j] + cbv[j] + dd[j] + qq[j];
        ev[j] = v;
        if (ESTATS) { psum[j] += v; psq[j] += v * v; }
      }
      *(uint4*)(eh16 + (size_t)p * 64 + cb) = pk8(ev);
    }
  }
  if (ESTATS) {
    float* red = (float*)esU;   // 64*65 = 4160 floats < 8192
    __syncthreads();
    #pragma unroll
    for (int j = 0; j < 8; ++j) red[rg * 65 + cb + j] = psum[j];
    __syncthreads();
    if (t < 64) {
      float s = 0.f;
      #pragma unroll
      for (int i = 0; i < 64; ++i) s += red[i * 65 + t];
      atomAddD(stats + 128 + t, (double)s);
    }
    __syncthreads();
    #pragma unroll
    for (int j = 0; j < 8; ++j) red[rg * 65 + cb + j] = psq[j];
    __syncthreads();
    if (t < 64) {
      float q = 0.f;
      #pragma unroll
      for (int i = 0; i < 64; ++i) q += red[i * 65 + t];
      atomAddD(stats + 192 + t, (double)q);
    }
  }
}

// ---------------- aggregation: 128 nodes/block, 1024 threads, 2 cols/thread ---------
// LAST==1 (layer 2): finalize also zeroes hg/counts for the readout.
template <int LAST>
__global__ __launch_bounds__(1024) void k_agg(const int* __restrict__ offs,
    const int* __restrict__ srcp, const __half* __restrict__ eh16,
    const __half* __restrict__ Bh16, __half* __restrict__ Ah16, double* __restrict__ stats,
    int* __restrict__ ctr,
    const float* __restrict__ hgam, const float* __restrict__ hbet,
    const float* __restrict__ egam, const float* __restrict__ ebet,
    float* __restrict__ bnp, float* __restrict__ hg) {
  int t = threadIdx.x;
  int c2 = (t & 31) * 2;     // column pair
  int g = t >> 5;            // 0..31 node groups
  float psx = 0.f, psy = 0.f, pqx = 0.f, pqy = 0.f;
  #pragma unroll 1
  for (int sub = 0; sub < 4; ++sub) {
    int n = blockIdx.x * 128 + g * 4 + sub;
    if (n < NN) {
      int i0 = offs[n], i1 = offs[n + 1];
      float nx = 0.f, ny = 0.f, dx = 0.f, dy = 0.f;
      int i = i0;
      #pragma unroll 1
      for (; i + 3 < i1; i += 4) {
        unsigned xu0 = *(const unsigned*)(eh16 + (size_t)(i + 0) * 64 + c2);
        unsigned xu1 = *(const unsigned*)(eh16 + (size_t)(i + 1) * 64 + c2);
        unsigned xu2 = *(const unsigned*)(eh16 + (size_t)(i + 2) * 64 + c2);
        unsigned xu3 = *(const unsigned*)(eh16 + (size_t)(i + 3) * 64 + c2);
        int s0 = srcp[i], s1 = srcp[i + 1], s2 = srcp[i + 2], s3 = srcp[i + 3];
        unsigned bu0 = *(const unsigned*)(Bh16 + (size_t)s0 * 64 + c2);
        unsigned bu1 = *(const unsigned*)(Bh16 + (size_t)s1 * 64 + c2);
        unsigned bu2 = *(const unsigned*)(Bh16 + (size_t)s2 * 64 + c2);
        unsigned bu3 = *(const unsigned*)(Bh16 + (size_t)s3 * 64 + c2);
        float2 x0 = up2h(xu0), x1 = up2h(xu1), x2 = up2h(xu2), x3 = up2h(xu3);
        float2 b0 = up2h(bu0), b1 = up2h(bu1), b2 = up2h(bu2), b3 = up2h(bu3);
        float g0x = 1.0f / (1.0f + __expf(-x0.x)), g0y = 1.0f / (1.0f + __expf(-x0.y));
        float g1x = 1.0f / (1.0f + __expf(-x1.x)), g1y = 1.0f / (1.0f + __expf(-x1.y));
        float g2x = 1.0f / (1.0f + __expf(-x2.x)), g2y = 1.0f / (1.0f + __expf(-x2.y));
        float g3x = 1.0f / (1.0f + __expf(-x3.x)), g3y = 1.0f / (1.0f + __expf(-x3.y));
        nx += g0x * b0.x + g1x * b1.x + g2x * b2.x + g3x * b3.x;
        ny += g0y * b0.y + g1y * b1.y + g2y * b2.y + g3y * b3.y;
        dx += g0x + g1x + g2x + g3x;
        dy += g0y + g1y + g2y + g3y;
      }
      #pragma unroll 1
      for (; i < i1; ++i) {
        unsigned xu = *(const unsigned*)(eh16 + (size_t)i * 64 + c2);
        int s0 = srcp[i];
        unsigned bu = *(const unsigned*)(Bh16 + (size_t)s0 * 64 + c2);
        float2 x = up2h(xu), b = up2h(bu);
        float gx = 1.0f / (1.0f + __expf(-x.x)), gy = 1.0f / (1.0f + __expf(-x.y));
        nx += gx * b.x; ny += gy * b.y;
        dx += gx; dy += gy;
      }
      size_t idx = (size_t)n * 64 + c2;
      float2 a = up2h(*(const unsigned*)(Ah16 + idx));
      float vx = a.x + nx / (dx + 1e-6f);
      float vy = a.y + ny / (dy + 1e-6f);
      *(unsigned*)(Ah16 + idx) = pk2h(vx, vy);
      psx += vx; psy += vy;
      pqx += vx * vx; pqy += vy * vy;
    }
  }
  __shared__ float2 red2[1024];
  red2[t] = make_float2(psx, psy); __syncthreads();
  if (t < 64) {
    int p = t >> 1, j = t & 1;
    float s = 0.f;
    #pragma unroll
    for (int i = 0; i < 32; ++i) {
      float2 v = red2[i * 32 + p];
      s += j ? v.y : v.x;
    }
    atomAddD(stats + t, (double)s);
  }
  __syncthreads();
  red2[t] = make_float2(pqx, pqy); __syncthreads();
  if (t < 64) {
    int p = t >> 1, j = t & 1;
    float q = 0.f;
    #pragma unroll
    for (int i = 0; i < 32; ++i) {
      float2 v = red2[i * 32 + p];
      q += j ? v.y : v.x;
    }
    atomAddD(stats + 64 + t, (double)q);
  }
  // ---- last-block finalize: compute BN scale/shift, reset stats ----
  __shared__ int lastFlag;
  __syncthreads();
  if (t == 0) {
    __threadfence();
    int old = atomAddI(ctr, 1);
    lastFlag = (old == (int)gridDim.x - 1);
  }
  __syncthreads();
  if (!lastFlag) return;
  if (t < 64) {
    double s = atomAddD(stats + t, 0.0);
    double q = atomAddD(stats + 64 + t, 0.0);
    double mu = s * (1.0 / NN);
    double var = q * (1.0 / NN) - mu * mu;
    float sc = hgam[t] / sqrtf((float)var + 1e-5f);
    bnp[t] = sc;
    bnp[64 + t] = hbet[t] - (float)mu * sc;
  } else if (t < 128) {
    int cc = t - 64;
    double s = atomAddD(stats + 128 + cc, 0.0);
    double q = atomAddD(stats + 192 + cc, 0.0);
    double mu = s * (1.0 / NE);
    double var = q * (1.0 / NE) - mu * mu;
    float sc = egam[cc] / sqrtf((float)var + 1e-5f);
    bnp[128 + cc] = sc;
    bnp[192 + cc] = ebet[cc] - (float)mu * sc;
  }
  __syncthreads();
  if (t < 256) atomicExch((unsigned long long*)&stats[t], 0ull);
  if (LAST) {
    for (int i = t; i < 1040; i += 1024) hg[i] = 0.f;
  }
}

// ---------------- readout with fused final h-residual (256 nodes/block) ------------
__global__ __launch_bounds__(256) void k_readout(const float* __restrict__ h,
    const __half* __restrict__ Ah16, const float* __restrict__ bnp,
    const int* __restrict__ gid, float* __restrict__ hg, float* __restrict__ counts) {
  int t = threadIdx.x;
  int c = t & 63;
  int ro = t >> 6;
  int nbase = blockIdx.x * 256;
  float sc = bnp[c], sh = bnp[64 + c];
  float sum = 0.f, cnt = 0.f;
  int curg = -1;
  #pragma unroll 1
  for (int i = 0; i < 64; ++i) {
    int n = nbase + ro + i * 4;
    if (n >= NN) break;
    int g = gid[n];
    if (g != curg) {
      if (curg >= 0) {
        atomAddF(&hg[curg * 64 + c], sum);
        if (c == 0) atomAddF(&counts[curg], cnt);
      }
      curg = g; sum = 0.f; cnt = 0.f;
    }
    size_t idx = (size_t)n * 64 + c;
    float av = __half2float(Ah16[idx]);
    sum += h[idx] + fmaxf(av * sc + sh, 0.f);
    cnt += 1.f;
  }
  if (curg >= 0) {
    atomAddF(&hg[curg * 64 + c], sum);
    if (c == 0) atomAddF(&counts[curg], cnt);
  }
}

// ---------------- final MLP (16 graphs), one block ----------------
__global__ __launch_bounds__(256) void k_mlp(const float* __restrict__ hg, const float* __restrict__ counts,
    const float* __restrict__ state,
    const float* __restrict__ w1, const float* __restrict__ b1,
    const float* __restrict__ w2, const float* __restrict__ b2,
    const float* __restrict__ w3, const float* __restrict__ b3,
    float* __restrict__ out) {
  __shared__ float x0[16][68];
  __shared__ float x1[16][256];
  __shared__ float x2[16][256];
  int t = threadIdx.x;
  for (int idx = t; idx < 16 * 68; idx += 256) {
    int g = idx / 68, c = idx % 68;
    x0[g][c] = (c < 64) ? hg[g * 64 + c] / counts[g] : state[g * 4 + (c - 64)];
  }
  __syncthreads();
  {
    float acc[16];
    float bb = b1[t];
    #pragma unroll
    for (int g = 0; g < 16; ++g) acc[g] = bb;
    for (int k = 0; k < 68; ++k) {
      float w = w1[k * 256 + t];
      #pragma unroll
      for (int g = 0; g < 16; ++g) acc[g] += x0[g][k] * w;
    }
    #pragma unroll
    for (int g = 0; g < 16; ++g) x1[g][t] = fmaxf(acc[g], 0.f);
  }
  __syncthreads();
  {
    float acc[16];
    float bb = b2[t];
    #pragma unroll
    for (int g = 0; g < 16; ++g) acc[g] = bb;
    for (int k = 0; k < 256; ++k) {
      float w = w2[k * 256 + t];
      #pragma unroll
      for (int g = 0; g < 16; ++g) acc[g] += x1[g][k] * w;
    }
    #pragma unroll
    for (int g = 0; g < 16; ++g) x2[g][t] = fmaxf(acc[g], 0.f);
  }
  __syncthreads();
  if (t < 32) {
    int g = t >> 1, o = t & 1;
    float acc = b3[o];
    for (int k = 0; k < 256; ++k) acc += x2[g][k] * w3[k * 2 + o];
    out[g * 2 + o] = tanhf(acc);
  }
}

extern "C" void kernel_launch(void* const* d_in, const int* in_sizes, int n_in,
                              void* d_out, int out_size, void* d_ws, size_t ws_size,
                              hipStream_t stream) {
  const float* state   = (const float*)d_in[0];
  const float* h_feat  = (const float*)d_in[1];
  const float* e_feat  = (const float*)d_in[2];
  const int*   src     = (const int*)d_in[3];
  const int*   dst     = (const int*)d_in[4];
  const int*   gid     = (const int*)d_in[5];
  const float* emb_h_w = (const float*)d_in[6];
  const float* emb_h_b = (const float*)d_in[7];
  const float* emb_e_w = (const float*)d_in[8];
  const float* emb_e_b = (const float*)d_in[9];
  const float* A_w = (const float*)d_in[10];
  const float* A_b = (const float*)d_in[11];
  const float* B_w = (const float*)d_in[12];
  const float* B_b = (const float*)d_in[13];
  const float* C_w = (const float*)d_in[14];
  const float* C_b = (const float*)d_in[15];
  const float* D_w = (const float*)d_in[16];
  const float* D_b = (const float*)d_in[17];
  const float* E_w = (const float*)d_in[18];
  const float* E_b = (const float*)d_in[19];
  const float* bn_h_g = (const float*)d_in[20];
  const float* bn_h_b = (const float*)d_in[21];
  const float* bn_e_g = (const float*)d_in[22];
  const float* bn_e_b = (const float*)d_in[23];
  const float* l1_w = (const float*)d_in[24];
  const float* l1_b = (const float*)d_in[25];
  const float* l2_w = (const float*)d_in[26];
  const float* l2_b = (const float*)d_in[27];
  const float* l3_w = (const float*)d_in[28];
  const float* l3_b = (const float*)d_in[29];

  float* wsp = (float*)d_ws;

  const size_t F_H = (size_t)NN * 64;       // fp32 node array (floats)
  const size_t F_H2 = (size_t)NN * 32;      // fp16 node array (float units)
  const size_t F_E2 = (size_t)NE * 32;      // fp16 edge array (float units)
  size_t off = 0;
  float*  h     = wsp + off; off += F_H;
  __half* Ah16  = (__half*)(wsp + off); off += F_H2;
  __half* e16   = (__half*)(wsp + off); off += F_E2;
  __half* eh16  = (__half*)(wsp + off); off += F_E2;
  float*  ef2   = wsp + off; off += (size_t)NE * 2;
  __half* Bh16  = (__half*)(wsp + off); off += F_H2;
  __half* Dh16  = (__half*)(wsp + off); off += F_H2;
  __half* Eh16  = (__half*)(wsp + off); off += F_H2;
  int* srcp    = (int*)(wsp + off); off += NE;
  int* dstp    = (int*)(wsp + off); off += NE;
  int* offs    = (int*)(wsp + off); off += NN + 4;
  int* degcur  = (int*)(wsp + off); off += NN + 4;   // deg/cursor + 3 ctrs + pad
  double* stats = (double*)(wsp + off); off += 512;
  float* bnp    = wsp + off; off += 256;
  float* hg     = wsp + off; off += 1024;
  float* counts = hg + 1024; off += 16;
  const size_t need = off * sizeof(float);
  if (ws_size < need) return;
  int* ctr = degcur + NN;   // 3 layer counters

  // CSR build (zero also clears the 3 counters)
  k_zero<<<64, 256, 0, stream>>>((float4*)degcur, (NN + 4) / 4);
  k_deg<<<(NE + 255) / 256, 256, 0, stream>>>(dst, degcur);
  k_scan<<<1, 1024, 0, stream>>>(degcur, offs, stats);
  k_scatter<<<(NE + 255) / 256, 256, 0, stream>>>(dst, src, e_feat, degcur, srcp, dstp, ef2);

  const int GN = (NN + 255) / 256;
  const int GE = (NE + 255) / 256;
  const int GA = (NN + 127) / 128;
  for (int l = 0; l < 3; ++l) {
    if (l == 0)
      k_node_gemm<2><<<GN, 512, 0, stream>>>(h, Ah16, bnp, h_feat, emb_h_w, emb_h_b,
          A_w, B_w, D_w, E_w, A_b, B_b, D_b, E_b, Ah16, Bh16, Dh16, Eh16);
    else
      k_node_gemm<1><<<GN, 512, 0, stream>>>(h, Ah16, bnp, h_feat, emb_h_w, emb_h_b,
          A_w + l * 4096, B_w + l * 4096, D_w + l * 4096, E_w + l * 4096,
          A_b + l * 64, B_b + l * 64, D_b + l * 64, E_b + l * 64,
          Ah16, Bh16, Dh16, Eh16);
    if (l == 0)
      k_edge_f<2, 1, 1><<<GE, 512, 0, stream>>>(e16, eh16, C_w, C_b,
          srcp, dstp, Dh16, Eh16, bnp, stats, ef2, emb_e_w, emb_e_b);
    else if (l == 1)
      k_edge_f<1, 1, 1><<<GE, 512, 0, stream>>>(e16, eh16, C_w + 4096, C_b + 64,
          srcp, dstp, Dh16, Eh16, bnp, stats, ef2, emb_e_w, emb_e_b);
    else
      k_edge_f<1, 0, 0><<<GE, 512, 0, stream>>>(e16, eh16, C_w + 8192, C_b + 128,
          srcp, dstp, Dh16, Eh16, bnp, stats, ef2, emb_e_w, emb_e_b);
    if (l < 2)
      k_agg<0><<<GA, 1024, 0, stream>>>(offs, srcp, eh16, Bh16, Ah16, stats, ctr + l,
          bn_h_g + l * 64, bn_h_b + l * 64, bn_e_g + l * 64, bn_e_b + l * 64, bnp, hg);
    else
      k_agg<1><<<GA, 1024, 0, stream>>>(offs, srcp, eh16, Bh16, Ah16, stats, ctr + l,
          bn_h_g + l * 64, bn_h_b + l * 64, bn_e_g + l * 64, bn_e_b + l * 64, bnp, hg);
  }
  k_readout<<<(NN + 255) / 256, 256, 0, stream>>>(h, Ah16, bnp, gid, hg, counts);
  k_mlp<<<1, 256, 0, stream>>>(hg, counts, state,
      l1_w, l1_b, l2_w, l2_b, l3_w, l3_b, (float*)d_out);
}

// Round 19
// 584.172 us; speedup vs baseline: 1.0298x; 1.0298x over previous
//
#include <hip/hip_runtime.h>
#include <hip/hip_fp16.h>
#include <math.h>
#include <string.h>

#define NN 50000
#define NE 400000

__device__ __forceinline__ void atomAddF(float* p, float v) { unsafeAtomicAdd(p, v); }
__device__ __forceinline__ double atomAddD(double* p, double v) { return unsafeAtomicAdd(p, v); }
__device__ __forceinline__ int atomAddI(int* p, int v) { return atomicAdd(p, v); }

typedef _Float16 h2v __attribute__((ext_vector_type(2)));

__device__ __forceinline__ float2 up2h(unsigned v) {
  __half2 h; memcpy(&h, &v, 4); return __half22float2(h);
}
__device__ __forceinline__ unsigned pk2h(float a, float b) {
  __half2 h = __floats2half2_rn(a, b);
  unsigned v; memcpy(&v, &h, 4); return v;
}
__device__ __forceinline__ void up8(uint4 u, float* f) {
  float2 a = up2h(u.x), b = up2h(u.y), c = up2h(u.z), d = up2h(u.w);
  f[0] = a.x; f[1] = a.y; f[2] = b.x; f[3] = b.y;
  f[4] = c.x; f[5] = c.y; f[6] = d.x; f[7] = d.y;
}
__device__ __forceinline__ uint4 pk8(const float* f) {
  uint4 u;
  u.x = pk2h(f[0], f[1]); u.y = pk2h(f[2], f[3]);
  u.z = pk2h(f[4], f[5]); u.w = pk2h(f[6], f[7]);
  return u;
}

#if __has_builtin(__builtin_amdgcn_fdot2)
__device__ __forceinline__ float dot2(unsigned a, unsigned b, float c) {
  return __builtin_amdgcn_fdot2(__builtin_bit_cast(h2v, a), __builtin_bit_cast(h2v, b), c, false);
}
#else
__device__ __forceinline__ float dot2(unsigned a, unsigned b, float c) {
  float2 fa = up2h(a), fb = up2h(b);
  return c + fa.x * fb.x + fa.y * fb.y;
}
#endif

// swizzle for half2-pair LDS tiles: keeps 4-row alignment (low 2 bits zero)
#define SW(kk) ((((kk) & 7)) << 2)

// ---------------- zero fill ----------------
__global__ __launch_bounds__(256) void k_zero(float4* __restrict__ p, int n4) {
  int i = blockIdx.x * 256 + threadIdx.x;
  int s = gridDim.x * 256;
  for (; i < n4; i += s) p[i] = make_float4(0.f, 0.f, 0.f, 0.f);
}

// ---------------- CSR build ----------------
__global__ __launch_bounds__(256) void k_deg(const int* __restrict__ dst, int* __restrict__ deg) {
  int i = blockIdx.x * 256 + threadIdx.x;
  if (i < NE) atomAddI(&deg[dst[i]], 1);
}

__global__ __launch_bounds__(1024) void k_scan(int* __restrict__ degcur,
    int* __restrict__ offs, double* __restrict__ stats) {
  __shared__ int wsum[16];
  int t = threadIdx.x;
  int lane = t & 63, w = t >> 6;
  if (t < 256) stats[t] = 0.0;
  int carry = 0;
  for (int base = 0; base < NN; base += 1024) {
    int i = base + t;
    int v = (i < NN) ? degcur[i] : 0;
    int x = v;
    #pragma unroll
    for (int off = 1; off < 64; off <<= 1) {
      int y = __shfl_up(x, off);
      if (lane >= off) x += y;
    }
    if (lane == 63) wsum[w] = x;
    __syncthreads();
    if (w == 0 && lane < 16) {
      int s = wsum[lane];
      #pragma unroll
      for (int off = 1; off < 16; off <<= 1) {
        int y = __shfl_up(s, off);
        if (lane >= off) s += y;
      }
      wsum[lane] = s;
    }
    __syncthreads();
    int wbase = (w > 0) ? wsum[w - 1] : 0;
    int total = wsum[15];
    int excl = carry + wbase + x - v;
    if (i < NN) { offs[i] = excl; degcur[i] = excl; }
    carry += total;
    __syncthreads();
  }
  if (t == 0) offs[NN] = carry;
}

__global__ __launch_bounds__(256) void k_scatter(const int* __restrict__ dst,
    const int* __restrict__ src, const float* __restrict__ e_feat,
    int* __restrict__ cursor,
    int* __restrict__ srcp, int* __restrict__ dstp, float* __restrict__ ef2) {
  int i = blockIdx.x * 256 + threadIdx.x;
  if (i < NE) {
    int d = dst[i];
    int p = atomAddI(&cursor[d], 1);
    srcp[p] = src[i];
    dstp[p] = d;
    ((float2*)ef2)[p] = ((const float2*)e_feat)[i];
  }
}

// ---------------- node GEMM, 256-row tile, 512 threads, half2-pair LDS + dot2 -------
// MODE==2 (layer 0): compute h = hf@emb_w + emb_b during staging, write h (fp32).
// MODE==1: h_new = h + relu(Ah16*sc + sh); write h back (fp32). GEMM uses fp16(h).
// Outputs: Ah16/Bh/Dh/Eh fp16.
template <int MODE>
__global__ __launch_bounds__(512) void k_node_gemm(float* __restrict__ h,
    const __half* __restrict__ Ah_in, const float* __restrict__ bnp,
    const float* __restrict__ hf, const float* __restrict__ ehw,
    const float* __restrict__ ehb,
    const float* __restrict__ w0, const float* __restrict__ w1,
    const float* __restrict__ w2, const float* __restrict__ w3,
    const float* __restrict__ b0, const float* __restrict__ b1,
    const float* __restrict__ b2, const float* __restrict__ b3,
    __half* __restrict__ Ah16, __half* __restrict__ Bh16,
    __half* __restrict__ Dh16, __half* __restrict__ Eh16) {
  __shared__ __align__(16) unsigned hsU[32 * 256];   // [kk][row ^ SW(kk)] half2, 32KB
  __shared__ __align__(16) unsigned wshU[32 * 64];   // [kk][col] half2, 8KB
  int t = threadIdx.x;
  int n0 = blockIdx.x * 256;
  #pragma unroll
  for (int i = 0; i < 8; ++i) {
    int f = (t + i * 512) * 4;
    int r = f >> 6;          // 0..255
    int k = f & 63;          // multiple of 4
    int n = n0 + r;
    float4 v = make_float4(0.f, 0.f, 0.f, 0.f);
    if (n < NN) {
      size_t idx = (size_t)n * 64 + k;
      if (MODE == 2) {
        const float* row = hf + (size_t)n * 6;
        v = *(const float4*)(ehb + k);
        #pragma unroll
        for (int q = 0; q < 6; ++q) {
          float x = row[q];
          float4 wv = *(const float4*)(ehw + q * 64 + k);
          v.x += x * wv.x; v.y += x * wv.y; v.z += x * wv.z; v.w += x * wv.w;
        }
        *(float4*)(h + idx) = v;
      } else {
        v = *(const float4*)(h + idx);
        if (MODE == 1) {
          uint2 au = *(const uint2*)(Ah_in + idx);
          float2 a01 = up2h(au.x), a23 = up2h(au.y);
          float4 sc4 = *(const float4*)(bnp + k);
          float4 sh4 = *(const float4*)(bnp + 64 + k);
          v.x += fmaxf(a01.x * sc4.x + sh4.x, 0.f);
          v.y += fmaxf(a01.y * sc4.y + sh4.y, 0.f);
          v.z += fmaxf(a23.x * sc4.z + sh4.z, 0.f);
          v.w += fmaxf(a23.y * sc4.w + sh4.w, 0.f);
          *(float4*)(h + idx) = v;
        }
      }
    }
    int kk0 = k >> 1;        // multiple of 2
    hsU[(kk0 + 0) * 256 + (r ^ SW(kk0 + 0))] = pk2h(v.x, v.y);
    hsU[(kk0 + 1) * 256 + (r ^ SW(kk0 + 1))] = pk2h(v.z, v.w);
  }
  int cg = t & 7, rg = t >> 3;   // rg 0..63 (4 rows each), cg 0..7 (8 cols)
  int cb = cg * 8;
  #pragma unroll 1
  for (int y = 0; y < 4; ++y) {
    const float* W = (y == 0) ? w0 : (y == 1) ? w1 : (y == 2) ? w2 : w3;
    const float* B = (y == 0) ? b0 : (y == 1) ? b1 : (y == 2) ? b2 : b3;
    __syncthreads();
    #pragma unroll
    for (int i = 0; i < 4; ++i) {
      int idx = t + i * 512;     // 0..2047
      int kk = idx >> 6, j = idx & 63;
      wshU[idx] = pk2h(W[(2 * kk) * 64 + j], W[(2 * kk + 1) * 64 + j]);
    }
    __syncthreads();
    float acc[4][8];
    #pragma unroll
    for (int r = 0; r < 4; ++r)
      #pragma unroll
      for (int j = 0; j < 8; ++j) acc[r][j] = 0.f;
    #pragma unroll 8
    for (int kk = 0; kk < 32; ++kk) {
      uint4 a4 = *(const uint4*)&hsU[kk * 256 + ((rg * 4) ^ SW(kk))];
      uint4 wA = *(const uint4*)&wshU[kk * 64 + cb];
      uint4 wB = *(const uint4*)&wshU[kk * 64 + cb + 4];
      unsigned av[4] = {a4.x, a4.y, a4.z, a4.w};
      unsigned wv[8] = {wA.x, wA.y, wA.z, wA.w, wB.x, wB.y, wB.z, wB.w};
      #pragma unroll
      for (int r = 0; r < 4; ++r)
        #pragma unroll
        for (int j = 0; j < 8; ++j) acc[r][j] = dot2(av[r], wv[j], acc[r][j]);
    }
    float4 bv0 = *(const float4*)(B + cb);
    float4 bv1 = *(const float4*)(B + cb + 4);
    float bv[8] = {bv0.x, bv0.y, bv0.z, bv0.w, bv1.x, bv1.y, bv1.z, bv1.w};
    __half* oh = (y == 0) ? Ah16 : (y == 1) ? Bh16 : (y == 2) ? Dh16 : Eh16;
    #pragma unroll
    for (int r = 0; r < 4; ++r) {
      int n = n0 + rg * 4 + r;
      if (n < NN) {
        float o[8];
        #pragma unroll
        for (int j = 0; j < 8; ++j) o[j] = acc[r][j] + bv[j];
        *(uint4*)(oh + (size_t)n * 64 + cb) = pk8(o);
      }
    }
  }
}

// ---------------- fused edge kernel, 256-row tile, 512 threads, half2-pair LDS ------
// MODE==1: e_new = e16 + relu(eh16_prev*sc+sh). MODE==2: compute e from raw CSR pairs
// ef2 + embedding (layer 0). EWRITE: persist e16.
// ehat = e@Cw + Cb + Dh16[srcp] + Eh16[dstp]; store fp16; ESTATS: e-BN stats.
template <int MODE, int ESTATS, int EWRITE>
__global__ __launch_bounds__(512) void k_edge_f(__half* __restrict__ e16,
    __half* __restrict__ eh16,
    const float* __restrict__ Cw, const float* __restrict__ Cb,
    const int* __restrict__ srcp, const int* __restrict__ dstp,
    const __half* __restrict__ Dh16, const __half* __restrict__ Eh16,
    const float* __restrict__ bnp, double* __restrict__ stats,
    const float* __restrict__ ef2, const float* __restrict__ ew,
    const float* __restrict__ eb) {
  __shared__ __align__(16) unsigned esU[32 * 256];   // [kk][row ^ SW(kk)] half2, 32KB
  __shared__ __align__(16) unsigned cwU[32 * 64];    // [kk][col] half2, 8KB
  int t = threadIdx.x;
  int e0 = blockIdx.x * 256;
  #pragma unroll
  for (int i = 0; i < 4; ++i) {
    int idx = t + i * 512;
    int kk = idx >> 6, j = idx & 63;
    cwU[idx] = pk2h(Cw[(2 * kk) * 64 + j], Cw[(2 * kk + 1) * 64 + j]);
  }
  #pragma unroll
  for (int i = 0; i < 4; ++i) {
    int f = (t + i * 512) * 8;
    int r = f >> 6;          // 0..255
    int k = f & 63;          // multiple of 8
    int row = e0 + r;
    uint4 raw = make_uint4(0u, 0u, 0u, 0u);
    if (row < NE) {
      size_t idx = (size_t)row * 64 + k;
      if (MODE == 2) {
        float2 rp = ((const float2*)ef2)[row];
        float r0 = 1.0f / rp.x;
        float r1 = 1.0f / rp.y;
        float4 bA = *(const float4*)(eb + k), bB = *(const float4*)(eb + k + 4);
        float4 waA = *(const float4*)(ew + k), waB = *(const float4*)(ew + k + 4);
        float4 wbA = *(const float4*)(ew + 64 + k), wbB = *(const float4*)(ew + 64 + k + 4);
        float v[8];
        v[0] = bA.x + r0 * waA.x + r1 * wbA.x;
        v[1] = bA.y + r0 * waA.y + r1 * wbA.y;
        v[2] = bA.z + r0 * waA.z + r1 * wbA.z;
        v[3] = bA.w + r0 * waA.w + r1 * wbA.w;
        v[4] = bB.x + r0 * waB.x + r1 * wbB.x;
        v[5] = bB.y + r0 * waB.y + r1 * wbB.y;
        v[6] = bB.z + r0 * waB.z + r1 * wbB.z;
        v[7] = bB.w + r0 * waB.w + r1 * wbB.w;
        raw = pk8(v);
        if (EWRITE) *(uint4*)(e16 + idx) = raw;
      } else {
        raw = *(const uint4*)(e16 + idx);
        if (MODE == 1) {
          float v[8], pp[8];
          up8(raw, v);
          up8(*(const uint4*)(eh16 + idx), pp);
          float4 scA = *(const float4*)(bnp + 128 + k);
          float4 scB = *(const float4*)(bnp + 128 + k + 4);
          float4 shA = *(const float4*)(bnp + 192 + k);
          float4 shB = *(const float4*)(bnp + 192 + k + 4);
          float sc[8] = {scA.x, scA.y, scA.z, scA.w, scB.x, scB.y, scB.z, scB.w};
          float sh[8] = {shA.x, shA.y, shA.z, shA.w, shB.x, shB.y, shB.z, shB.w};
          #pragma unroll
          for (int j = 0; j < 8; ++j) v[j] += fmaxf(pp[j] * sc[j] + sh[j], 0.f);
          raw = pk8(v);
          if (EWRITE) *(uint4*)(e16 + idx) = raw;
        }
      }
    }
    int kk0 = k >> 1;        // multiple of 4
    esU[(kk0 + 0) * 256 + (r ^ SW(kk0 + 0))] = raw.x;
    esU[(kk0 + 1) * 256 + (r ^ SW(kk0 + 1))] = raw.y;
    esU[(kk0 + 2) * 256 + (r ^ SW(kk0 + 2))] = raw.z;
    esU[(kk0 + 3) * 256 + (r ^ SW(kk0 + 3))] = raw.w;
  }
  __syncthreads();
  int cg = t & 7, rg = t >> 3;   // rg 0..63 (4 rows each)
  int cb = cg * 8;
  float acc[4][8];
  #pragma unroll
  for (int r = 0; r < 4; ++r)
    #pragma unroll
    for (int j = 0; j < 8; ++j) acc[r][j] = 0.f;
  #pragma unroll 8
  for (int kk = 0; kk < 32; ++kk) {
    uint4 a4 = *(const uint4*)&esU[kk * 256 + ((rg * 4) ^ SW(kk))];
    uint4 wA = *(const uint4*)&cwU[kk * 64 + cb];
    uint4 wB = *(const uint4*)&cwU[kk * 64 + cb + 4];
    unsigned av[4] = {a4.x, a4.y, a4.z, a4.w};
    unsigned wv[8] = {wA.x, wA.y, wA.z, wA.w, wB.x, wB.y, wB.z, wB.w};
    #pragma unroll
    for (int r = 0; r < 4; ++r)
      #pragma unroll
      for (int j = 0; j < 8; ++j) acc[r][j] = dot2(av[r], wv[j], acc[r][j]);
  }
  float4 cb0 = *(const float4*)(Cb + cb);
  float4 cb1 = *(const float4*)(Cb + cb + 4);
  float cbv[8] = {cb0.x, cb0.y, cb0.z, cb0.w, cb1.x, cb1.y, cb1.z, cb1.w};
  float psum[8], psq[8];
  #pragma unroll
  for (int j = 0; j < 8; ++j) { psum[j] = 0.f; psq[j] = 0.f; }
  #pragma unroll
  for (int r = 0; r < 4; ++r) {
    int p = e0 + rg * 4 + r;
    if (p < NE) {
      int sN = srcp[p], dN = dstp[p];
      float dd[8], qq[8];
      up8(*(const uint4*)(Dh16 + (size_t)sN * 64 + cb), dd);
      up8(*(const uint4*)(Eh16 + (size_t)dN * 64 + cb), qq);
      float ev[8];
      #pragma unroll
      for (int j = 0; j < 8; ++j) {
        float v = acc[r][j] + cbv[j] + dd[j] + qq[j];
        ev[j] = v;
        if (ESTATS) { psum[j] += v; psq[j] += v * v; }
      }
      *(uint4*)(eh16 + (size_t)p * 64 + cb) = pk8(ev);
    }
  }
  if (ESTATS) {
    float* red = (float*)esU;   // 64*65 = 4160 floats < 8192
    __syncthreads();
    #pragma unroll
    for (int j = 0; j < 8; ++j) red[rg * 65 + cb + j] = psum[j];
    __syncthreads();
    if (t < 64) {
      float s = 0.f;
      #pragma unroll
      for (int i = 0; i < 64; ++i) s += red[i * 65 + t];
      atomAddD(stats + 128 + t, (double)s);
    }
    __syncthreads();
    #pragma unroll
    for (int j = 0; j < 8; ++j) red[rg * 65 + cb + j] = psq[j];
    __syncthreads();
    if (t < 64) {
      float q = 0.f;
      #pragma unroll
      for (int i = 0; i < 64; ++i) q += red[i * 65 + t];
      atomAddD(stats + 192 + t, (double)q);
    }
  }
}

// ---------------- aggregation: 128 nodes/block, 1024 threads, 1 col/thread ----------
// One node per 64-lane wave-group (uniform trip count). fp16 Ah read-modify-write.
// LAST==1 (layer 2): finalize also zeroes hg/counts for the readout.
template <int LAST>
__global__ __launch_bounds__(1024) void k_agg(const int* __restrict__ offs,
    const int* __restrict__ srcp, const __half* __restrict__ eh16,
    const __half* __restrict__ Bh16, __half* __restrict__ Ah16, double* __restrict__ stats,
    int* __restrict__ ctr,
    const float* __restrict__ hgam, const float* __restrict__ hbet,
    const float* __restrict__ egam, const float* __restrict__ ebet,
    float* __restrict__ bnp, float* __restrict__ hg) {
  int t = threadIdx.x;
  int c = t & 63;
  int g = t >> 6;   // 0..15
  float psum = 0.f, psq = 0.f;
  #pragma unroll 1
  for (int sub = 0; sub < 8; ++sub) {
    int n = blockIdx.x * 128 + g * 8 + sub;
    if (n < NN) {
      int i0 = offs[n], i1 = offs[n + 1];
      float num = 0.f, den = 0.f;
      int i = i0;
      #pragma unroll 1
      for (; i + 3 < i1; i += 4) {
        float x0 = __half2float(eh16[(size_t)(i + 0) * 64 + c]);
        float x1 = __half2float(eh16[(size_t)(i + 1) * 64 + c]);
        float x2 = __half2float(eh16[(size_t)(i + 2) * 64 + c]);
        float x3 = __half2float(eh16[(size_t)(i + 3) * 64 + c]);
        int s0 = srcp[i], s1 = srcp[i + 1], s2 = srcp[i + 2], s3 = srcp[i + 3];
        float b0 = __half2float(Bh16[(size_t)s0 * 64 + c]);
        float b1 = __half2float(Bh16[(size_t)s1 * 64 + c]);
        float b2 = __half2float(Bh16[(size_t)s2 * 64 + c]);
        float b3 = __half2float(Bh16[(size_t)s3 * 64 + c]);
        float g0 = 1.0f / (1.0f + __expf(-x0));
        float g1 = 1.0f / (1.0f + __expf(-x1));
        float g2 = 1.0f / (1.0f + __expf(-x2));
        float g3 = 1.0f / (1.0f + __expf(-x3));
        num += g0 * b0 + g1 * b1 + g2 * b2 + g3 * b3;
        den += g0 + g1 + g2 + g3;
      }
      #pragma unroll 1
      for (; i < i1; ++i) {
        float x0 = __half2float(eh16[(size_t)i * 64 + c]);
        int s0 = srcp[i];
        float b0 = __half2float(Bh16[(size_t)s0 * 64 + c]);
        float g0 = 1.0f / (1.0f + __expf(-x0));
        num += g0 * b0;
        den += g0;
      }
      size_t idx = (size_t)n * 64 + c;
      float v = __half2float(Ah16[idx]) + num / (den + 1e-6f);
      Ah16[idx] = __float2half(v);
      psum += v; psq += v * v;
    }
  }
  __shared__ float red[1024];
  red[t] = psum; __syncthreads();
  if (t < 64) {
    float s = 0.f;
    #pragma unroll
    for (int i = 0; i < 16; ++i) s += red[t + i * 64];
    atomAddD(stats + t, (double)s);
  }
  __syncthreads();
  red[t] = psq; __syncthreads();
  if (t < 64) {
    float q = 0.f;
    #pragma unroll
    for (int i = 0; i < 16; ++i) q += red[t + i * 64];
    atomAddD(stats + 64 + t, (double)q);
  }
  // ---- last-block finalize: compute BN scale/shift, reset stats ----
  __shared__ int lastFlag;
  __syncthreads();
  if (t == 0) {
    __threadfence();
    int old = atomAddI(ctr, 1);
    lastFlag = (old == (int)gridDim.x - 1);
  }
  __syncthreads();
  if (!lastFlag) return;
  if (t < 64) {
    double s = atomAddD(stats + t, 0.0);
    double q = atomAddD(stats + 64 + t, 0.0);
    double mu = s * (1.0 / NN);
    double var = q * (1.0 / NN) - mu * mu;
    float sc = hgam[t] / sqrtf((float)var + 1e-5f);
    bnp[t] = sc;
    bnp[64 + t] = hbet[t] - (float)mu * sc;
  } else if (t < 128) {
    int cc = t - 64;
    double s = atomAddD(stats + 128 + cc, 0.0);
    double q = atomAddD(stats + 192 + cc, 0.0);
    double mu = s * (1.0 / NE);
    double var = q * (1.0 / NE) - mu * mu;
    float sc = egam[cc] / sqrtf((float)var + 1e-5f);
    bnp[128 + cc] = sc;
    bnp[192 + cc] = ebet[cc] - (float)mu * sc;
  }
  __syncthreads();
  if (t < 256) atomicExch((unsigned long long*)&stats[t], 0ull);
  if (LAST) {
    for (int i = t; i < 1040; i += 1024) hg[i] = 0.f;
  }
}

// ---------------- readout with fused final h-residual (256 nodes/block) ------------
__global__ __launch_bounds__(256) void k_readout(const float* __restrict__ h,
    const __half* __restrict__ Ah16, const float* __restrict__ bnp,
    const int* __restrict__ gid, float* __restrict__ hg, float* __restrict__ counts) {
  int t = threadIdx.x;
  int c = t & 63;
  int ro = t >> 6;
  int nbase = blockIdx.x * 256;
  float sc = bnp[c], sh = bnp[64 + c];
  float sum = 0.f, cnt = 0.f;
  int curg = -1;
  #pragma unroll 1
  for (int i = 0; i < 64; ++i) {
    int n = nbase + ro + i * 4;
    if (n >= NN) break;
    int g = gid[n];
    if (g != curg) {
      if (curg >= 0) {
        atomAddF(&hg[curg * 64 + c], sum);
        if (c == 0) atomAddF(&counts[curg], cnt);
      }
      curg = g; sum = 0.f; cnt = 0.f;
    }
    size_t idx = (size_t)n * 64 + c;
    float av = __half2float(Ah16[idx]);
    sum += h[idx] + fmaxf(av * sc + sh, 0.f);
    cnt += 1.f;
  }
  if (curg >= 0) {
    atomAddF(&hg[curg * 64 + c], sum);
    if (c == 0) atomAddF(&counts[curg], cnt);
  }
}

// ---------------- final MLP (16 graphs), one block ----------------
__global__ __launch_bounds__(256) void k_mlp(const float* __restrict__ hg, const float* __restrict__ counts,
    const float* __restrict__ state,
    const float* __restrict__ w1, const float* __restrict__ b1,
    const float* __restrict__ w2, const float* __restrict__ b2,
    const float* __restrict__ w3, const float* __restrict__ b3,
    float* __restrict__ out) {
  __shared__ float x0[16][68];
  __shared__ float x1[16][256];
  __shared__ float x2[16][256];
  int t = threadIdx.x;
  for (int idx = t; idx < 16 * 68; idx += 256) {
    int g = idx / 68, c = idx % 68;
    x0[g][c] = (c < 64) ? hg[g * 64 + c] / counts[g] : state[g * 4 + (c - 64)];
  }
  __syncthreads();
  {
    float acc[16];
    float bb = b1[t];
    #pragma unroll
    for (int g = 0; g < 16; ++g) acc[g] = bb;
    for (int k = 0; k < 68; ++k) {
      float w = w1[k * 256 + t];
      #pragma unroll
      for (int g = 0; g < 16; ++g) acc[g] += x0[g][k] * w;
    }
    #pragma unroll
    for (int g = 0; g < 16; ++g) x1[g][t] = fmaxf(acc[g], 0.f);
  }
  __syncthreads();
  {
    float acc[16];
    float bb = b2[t];
    #pragma unroll
    for (int g = 0; g < 16; ++g) acc[g] = bb;
    for (int k = 0; k < 256; ++k) {
      float w = w2[k * 256 + t];
      #pragma unroll
      for (int g = 0; g < 16; ++g) acc[g] += x1[g][k] * w;
    }
    #pragma unroll
    for (int g = 0; g < 16; ++g) x2[g][t] = fmaxf(acc[g], 0.f);
  }
  __syncthreads();
  if (t < 32) {
    int g = t >> 1, o = t & 1;
    float acc = b3[o];
    for (int k = 0; k < 256; ++k) acc += x2[g][k] * w3[k * 2 + o];
    out[g * 2 + o] = tanhf(acc);
  }
}

extern "C" void kernel_launch(void* const* d_in, const int* in_sizes, int n_in,
                              void* d_out, int out_size, void* d_ws, size_t ws_size,
                              hipStream_t stream) {
  const float* state   = (const float*)d_in[0];
  const float* h_feat  = (const float*)d_in[1];
  const float* e_feat  = (const float*)d_in[2];
  const int*   src     = (const int*)d_in[3];
  const int*   dst     = (const int*)d_in[4];
  const int*   gid     = (const int*)d_in[5];
  const float* emb_h_w = (const float*)d_in[6];
  const float* emb_h_b = (const float*)d_in[7];
  const float* emb_e_w = (const float*)d_in[8];
  const float* emb_e_b = (const float*)d_in[9];
  const float* A_w = (const float*)d_in[10];
  const float* A_b = (const float*)d_in[11];
  const float* B_w = (const float*)d_in[12];
  const float* B_b = (const float*)d_in[13];
  const float* C_w = (const float*)d_in[14];
  const float* C_b = (const float*)d_in[15];
  const float* D_w = (const float*)d_in[16];
  const float* D_b = (const float*)d_in[17];
  const float* E_w = (const float*)d_in[18];
  const float* E_b = (const float*)d_in[19];
  const float* bn_h_g = (const float*)d_in[20];
  const float* bn_h_b = (const float*)d_in[21];
  const float* bn_e_g = (const float*)d_in[22];
  const float* bn_e_b = (const float*)d_in[23];
  const float* l1_w = (const float*)d_in[24];
  const float* l1_b = (const float*)d_in[25];
  const float* l2_w = (const float*)d_in[26];
  const float* l2_b = (const float*)d_in[27];
  const float* l3_w = (const float*)d_in[28];
  const float* l3_b = (const float*)d_in[29];

  float* wsp = (float*)d_ws;

  const size_t F_H = (size_t)NN * 64;       // fp32 node array (floats)
  const size_t F_H2 = (size_t)NN * 32;      // fp16 node array (float units)
  const size_t F_E2 = (size_t)NE * 32;      // fp16 edge array (float units)
  size_t off = 0;
  float*  h     = wsp + off; off += F_H;
  __half* Ah16  = (__half*)(wsp + off); off += F_H2;
  __half* e16   = (__half*)(wsp + off); off += F_E2;
  __half* eh16  = (__half*)(wsp + off); off += F_E2;
  float*  ef2   = wsp + off; off += (size_t)NE * 2;
  __half* Bh16  = (__half*)(wsp + off); off += F_H2;
  __half* Dh16  = (__half*)(wsp + off); off += F_H2;
  __half* Eh16  = (__half*)(wsp + off); off += F_H2;
  int* srcp    = (int*)(wsp + off); off += NE;
  int* dstp    = (int*)(wsp + off); off += NE;
  int* offs    = (int*)(wsp + off); off += NN + 4;
  int* degcur  = (int*)(wsp + off); off += NN + 4;   // deg/cursor + 3 ctrs + pad
  double* stats = (double*)(wsp + off); off += 512;
  float* bnp    = wsp + off; off += 256;
  float* hg     = wsp + off; off += 1024;
  float* counts = hg + 1024; off += 16;
  const size_t need = off * sizeof(float);
  if (ws_size < need) return;
  int* ctr = degcur + NN;   // 3 layer counters

  // CSR build (zero also clears the 3 counters)
  k_zero<<<64, 256, 0, stream>>>((float4*)degcur, (NN + 4) / 4);
  k_deg<<<(NE + 255) / 256, 256, 0, stream>>>(dst, degcur);
  k_scan<<<1, 1024, 0, stream>>>(degcur, offs, stats);
  k_scatter<<<(NE + 255) / 256, 256, 0, stream>>>(dst, src, e_feat, degcur, srcp, dstp, ef2);

  const int GN = (NN + 255) / 256;
  const int GE = (NE + 255) / 256;
  const int GA = (NN + 127) / 128;
  for (int l = 0; l < 3; ++l) {
    if (l == 0)
      k_node_gemm<2><<<GN, 512, 0, stream>>>(h, Ah16, bnp, h_feat, emb_h_w, emb_h_b,
          A_w, B_w, D_w, E_w, A_b, B_b, D_b, E_b, Ah16, Bh16, Dh16, Eh16);
    else
      k_node_gemm<1><<<GN, 512, 0, stream>>>(h, Ah16, bnp, h_feat, emb_h_w, emb_h_b,
          A_w + l * 4096, B_w + l * 4096, D_w + l * 4096, E_w + l * 4096,
          A_b + l * 64, B_b + l * 64, D_b + l * 64, E_b + l * 64,
          Ah16, Bh16, Dh16, Eh16);
    if (l == 0)
      k_edge_f<2, 1, 1><<<GE, 512, 0, stream>>>(e16, eh16, C_w, C_b,
          srcp, dstp, Dh16, Eh16, bnp, stats, ef2, emb_e_w, emb_e_b);
    else if (l == 1)
      k_edge_f<1, 1, 1><<<GE, 512, 0, stream>>>(e16, eh16, C_w + 4096, C_b + 64,
          srcp, dstp, Dh16, Eh16, bnp, stats, ef2, emb_e_w, emb_e_b);
    else
      k_edge_f<1, 0, 0><<<GE, 512, 0, stream>>>(e16, eh16, C_w + 8192, C_b + 128,
          srcp, dstp, Dh16, Eh16, bnp, stats, ef2, emb_e_w, emb_e_b);
    if (l < 2)
      k_agg<0><<<GA, 1024, 0, stream>>>(offs, srcp, eh16, Bh16, Ah16, stats, ctr + l,
          bn_h_g + l * 64, bn_h_b + l * 64, bn_e_g + l * 64, bn_e_b + l * 64, bnp, hg);
    else
      k_agg<1><<<GA, 1024, 0, stream>>>(offs, srcp, eh16, Bh16, Ah16, stats, ctr + l,
          bn_h_g + l * 64, bn_h_b + l * 64, bn_e_g + l * 64, bn_e_b + l * 64, bnp, hg);
  }
  k_readout<<<(NN + 255) / 256, 256, 0, stream>>>(h, Ah16, bnp, gid, hg, counts);
  k_mlp<<<1, 256, 0, stream>>>(hg, counts, state,
      l1_w, l1_b, l2_w, l2_b, l3_w, l3_b, (float*)d_out);
}

// Round 20
// 549.163 us; speedup vs baseline: 1.0955x; 1.0638x over previous
//
#include <hip/hip_runtime.h>
#include <hip/hip_fp16.h>
#include <math.h>
#include <string.h>

#define NN 50000
#define NE 400000

__device__ __forceinline__ void atomAddF(float* p, float v) { unsafeAtomicAdd(p, v); }
__device__ __forceinline__ double atomAddD(double* p, double v) { return unsafeAtomicAdd(p, v); }
__device__ __forceinline__ int atomAddI(int* p, int v) { return atomicAdd(p, v); }

typedef _Float16 h2v __attribute__((ext_vector_type(2)));

__device__ __forceinline__ float2 up2h(unsigned v) {
  __half2 h; memcpy(&h, &v, 4); return __half22float2(h);
}
__device__ __forceinline__ unsigned pk2h(float a, float b) {
  __half2 h = __floats2half2_rn(a, b);
  unsigned v; memcpy(&v, &h, 4); return v;
}
__device__ __forceinline__ void up8(uint4 u, float* f) {
  float2 a = up2h(u.x), b = up2h(u.y), c = up2h(u.z), d = up2h(u.w);
  f[0] = a.x; f[1] = a.y; f[2] = b.x; f[3] = b.y;
  f[4] = c.x; f[5] = c.y; f[6] = d.x; f[7] = d.y;
}
__device__ __forceinline__ uint4 pk8(const float* f) {
  uint4 u;
  u.x = pk2h(f[0], f[1]); u.y = pk2h(f[2], f[3]);
  u.z = pk2h(f[4], f[5]); u.w = pk2h(f[6], f[7]);
  return u;
}

#if __has_builtin(__builtin_amdgcn_fdot2)
__device__ __forceinline__ float dot2(unsigned a, unsigned b, float c) {
  return __builtin_amdgcn_fdot2(__builtin_bit_cast(h2v, a), __builtin_bit_cast(h2v, b), c, false);
}
#else
__device__ __forceinline__ float dot2(unsigned a, unsigned b, float c) {
  float2 fa = up2h(a), fb = up2h(b);
  return c + fa.x * fb.x + fa.y * fb.y;
}
#endif

// swizzle for half2-pair LDS tiles: keeps 4-row alignment (low 2 bits zero)
#define SW(kk) ((((kk) & 7)) << 2)

// ---------------- zero fill ----------------
__global__ __launch_bounds__(256) void k_zero(float4* __restrict__ p, int n4) {
  int i = blockIdx.x * 256 + threadIdx.x;
  int s = gridDim.x * 256;
  for (; i < n4; i += s) p[i] = make_float4(0.f, 0.f, 0.f, 0.f);
}

// ---------------- CSR build ----------------
__global__ __launch_bounds__(256) void k_deg(const int* __restrict__ dst, int* __restrict__ deg) {
  int i = blockIdx.x * 256 + threadIdx.x;
  if (i < NE) atomAddI(&deg[dst[i]], 1);
}

// phase A: per-256-chunk local exclusive scan + block totals
__global__ __launch_bounds__(256) void k_scanA(const int* __restrict__ deg,
    int* __restrict__ locx, int* __restrict__ bsum) {
  __shared__ int wsum[4];
  int t = threadIdx.x;
  int i = blockIdx.x * 256 + t;
  int v = (i < NN) ? deg[i] : 0;
  int lane = t & 63, w = t >> 6;
  int x = v;
  #pragma unroll
  for (int off = 1; off < 64; off <<= 1) {
    int y = __shfl_up(x, off);
    if (lane >= off) x += y;
  }
  if (lane == 63) wsum[w] = x;
  __syncthreads();
  int wbase = 0;
  #pragma unroll
  for (int j = 0; j < 4; ++j) if (j < w) wbase += wsum[j];
  if (i < NN) locx[i] = wbase + x - v;
  if (t == 255) bsum[blockIdx.x] = wbase + x;
}

// phase B: scan the block totals (nb <= 256); also zero stats for layer 0
__global__ __launch_bounds__(256) void k_scanB(int* __restrict__ bsum, int nb,
    double* __restrict__ stats) {
  __shared__ int wsum[4];
  int t = threadIdx.x;
  stats[t] = 0.0;
  int v = (t < nb) ? bsum[t] : 0;
  int lane = t & 63, w = t >> 6;
  int x = v;
  #pragma unroll
  for (int off = 1; off < 64; off <<= 1) {
    int y = __shfl_up(x, off);
    if (lane >= off) x += y;
  }
  if (lane == 63) wsum[w] = x;
  __syncthreads();
  int wbase = 0;
  #pragma unroll
  for (int j = 0; j < 4; ++j) if (j < w) wbase += wsum[j];
  if (t < nb) bsum[t] = wbase + x - v;
}

// phase C: add block base, write offs + cursor
__global__ __launch_bounds__(256) void k_scanC(const int* __restrict__ locx,
    const int* __restrict__ bsum, int* __restrict__ offs, int* __restrict__ cursor) {
  int i = blockIdx.x * 256 + threadIdx.x;
  if (i < NN) {
    int v = locx[i] + bsum[blockIdx.x];
    offs[i] = v;
    cursor[i] = v;
  }
  if (i == 0) offs[NN] = NE;
}

__global__ __launch_bounds__(256) void k_scatter(const int* __restrict__ dst,
    const int* __restrict__ src, const float* __restrict__ e_feat,
    int* __restrict__ cursor,
    int* __restrict__ srcp, int* __restrict__ dstp, float* __restrict__ ef2) {
  int i = blockIdx.x * 256 + threadIdx.x;
  if (i < NE) {
    int d = dst[i];
    int p = atomAddI(&cursor[d], 1);
    srcp[p] = src[i];
    dstp[p] = d;
    ((float2*)ef2)[p] = ((const float2*)e_feat)[i];
  }
}

// ---------------- node GEMM, 256-row tile, 512 threads, half2-pair LDS + dot2 -------
// MODE==2 (layer 0): compute h = hf@emb_w + emb_b during staging, write h (fp32).
// MODE==1: h_new = h + relu(Ah16*sc + sh); write h back (fp32). GEMM uses fp16(h).
// Outputs: Ah16/Bh/Dh/Eh fp16.
template <int MODE>
__global__ __launch_bounds__(512) void k_node_gemm(float* __restrict__ h,
    const __half* __restrict__ Ah_in, const float* __restrict__ bnp,
    const float* __restrict__ hf, const float* __restrict__ ehw,
    const float* __restrict__ ehb,
    const float* __restrict__ w0, const float* __restrict__ w1,
    const float* __restrict__ w2, const float* __restrict__ w3,
    const float* __restrict__ b0, const float* __restrict__ b1,
    const float* __restrict__ b2, const float* __restrict__ b3,
    __half* __restrict__ Ah16, __half* __restrict__ Bh16,
    __half* __restrict__ Dh16, __half* __restrict__ Eh16) {
  __shared__ __align__(16) unsigned hsU[32 * 256];   // [kk][row ^ SW(kk)] half2, 32KB
  __shared__ __align__(16) unsigned wshU[32 * 64];   // [kk][col] half2, 8KB
  int t = threadIdx.x;
  int n0 = blockIdx.x * 256;
  #pragma unroll
  for (int i = 0; i < 8; ++i) {
    int f = (t + i * 512) * 4;
    int r = f >> 6;          // 0..255
    int k = f & 63;          // multiple of 4
    int n = n0 + r;
    float4 v = make_float4(0.f, 0.f, 0.f, 0.f);
    if (n < NN) {
      size_t idx = (size_t)n * 64 + k;
      if (MODE == 2) {
        const float* row = hf + (size_t)n * 6;
        v = *(const float4*)(ehb + k);
        #pragma unroll
        for (int q = 0; q < 6; ++q) {
          float x = row[q];
          float4 wv = *(const float4*)(ehw + q * 64 + k);
          v.x += x * wv.x; v.y += x * wv.y; v.z += x * wv.z; v.w += x * wv.w;
        }
        *(float4*)(h + idx) = v;
      } else {
        v = *(const float4*)(h + idx);
        if (MODE == 1) {
          uint2 au = *(const uint2*)(Ah_in + idx);
          float2 a01 = up2h(au.x), a23 = up2h(au.y);
          float4 sc4 = *(const float4*)(bnp + k);
          float4 sh4 = *(const float4*)(bnp + 64 + k);
          v.x += fmaxf(a01.x * sc4.x + sh4.x, 0.f);
          v.y += fmaxf(a01.y * sc4.y + sh4.y, 0.f);
          v.z += fmaxf(a23.x * sc4.z + sh4.z, 0.f);
          v.w += fmaxf(a23.y * sc4.w + sh4.w, 0.f);
          *(float4*)(h + idx) = v;
        }
      }
    }
    int kk0 = k >> 1;        // multiple of 2
    hsU[(kk0 + 0) * 256 + (r ^ SW(kk0 + 0))] = pk2h(v.x, v.y);
    hsU[(kk0 + 1) * 256 + (r ^ SW(kk0 + 1))] = pk2h(v.z, v.w);
  }
  int cg = t & 7, rg = t >> 3;   // rg 0..63 (4 rows each), cg 0..7 (8 cols)
  int cb = cg * 8;
  #pragma unroll 1
  for (int y = 0; y < 4; ++y) {
    const float* W = (y == 0) ? w0 : (y == 1) ? w1 : (y == 2) ? w2 : w3;
    const float* B = (y == 0) ? b0 : (y == 1) ? b1 : (y == 2) ? b2 : b3;
    __syncthreads();
    #pragma unroll
    for (int i = 0; i < 4; ++i) {
      int idx = t + i * 512;     // 0..2047
      int kk = idx >> 6, j = idx & 63;
      wshU[idx] = pk2h(W[(2 * kk) * 64 + j], W[(2 * kk + 1) * 64 + j]);
    }
    __syncthreads();
    float acc[4][8];
    #pragma unroll
    for (int r = 0; r < 4; ++r)
      #pragma unroll
      for (int j = 0; j < 8; ++j) acc[r][j] = 0.f;
    #pragma unroll 8
    for (int kk = 0; kk < 32; ++kk) {
      uint4 a4 = *(const uint4*)&hsU[kk * 256 + ((rg * 4) ^ SW(kk))];
      uint4 wA = *(const uint4*)&wshU[kk * 64 + cb];
      uint4 wB = *(const uint4*)&wshU[kk * 64 + cb + 4];
      unsigned av[4] = {a4.x, a4.y, a4.z, a4.w};
      unsigned wv[8] = {wA.x, wA.y, wA.z, wA.w, wB.x, wB.y, wB.z, wB.w};
      #pragma unroll
      for (int r = 0; r < 4; ++r)
        #pragma unroll
        for (int j = 0; j < 8; ++j) acc[r][j] = dot2(av[r], wv[j], acc[r][j]);
    }
    float4 bv0 = *(const float4*)(B + cb);
    float4 bv1 = *(const float4*)(B + cb + 4);
    float bv[8] = {bv0.x, bv0.y, bv0.z, bv0.w, bv1.x, bv1.y, bv1.z, bv1.w};
    __half* oh = (y == 0) ? Ah16 : (y == 1) ? Bh16 : (y == 2) ? Dh16 : Eh16;
    #pragma unroll
    for (int r = 0; r < 4; ++r) {
      int n = n0 + rg * 4 + r;
      if (n < NN) {
        float o[8];
        #pragma unroll
        for (int j = 0; j < 8; ++j) o[j] = acc[r][j] + bv[j];
        *(uint4*)(oh + (size_t)n * 64 + cb) = pk8(o);
      }
    }
  }
}

// ---------------- fused edge kernel, 256-row tile, 512 threads, half2-pair LDS ------
// MODE==1: e_new = e16 + relu(eh16_prev*sc+sh). MODE==2: compute e from raw CSR pairs
// ef2 + embedding (layer 0). EWRITE: persist e16.
// ehat = e@Cw + Cb + Dh16[srcp] + Eh16[dstp]; store fp16; ESTATS: e-BN stats.
template <int MODE, int ESTATS, int EWRITE>
__global__ __launch_bounds__(512) void k_edge_f(__half* __restrict__ e16,
    __half* __restrict__ eh16,
    const float* __restrict__ Cw, const float* __restrict__ Cb,
    const int* __restrict__ srcp, const int* __restrict__ dstp,
    const __half* __restrict__ Dh16, const __half* __restrict__ Eh16,
    const float* __restrict__ bnp, double* __restrict__ stats,
    const float* __restrict__ ef2, const float* __restrict__ ew,
    const float* __restrict__ eb) {
  __shared__ __align__(16) unsigned esU[32 * 256];   // [kk][row ^ SW(kk)] half2, 32KB
  __shared__ __align__(16) unsigned cwU[32 * 64];    // [kk][col] half2, 8KB
  int t = threadIdx.x;
  int e0 = blockIdx.x * 256;
  #pragma unroll
  for (int i = 0; i < 4; ++i) {
    int idx = t + i * 512;
    int kk = idx >> 6, j = idx & 63;
    cwU[idx] = pk2h(Cw[(2 * kk) * 64 + j], Cw[(2 * kk + 1) * 64 + j]);
  }
  #pragma unroll
  for (int i = 0; i < 4; ++i) {
    int f = (t + i * 512) * 8;
    int r = f >> 6;          // 0..255
    int k = f & 63;          // multiple of 8
    int row = e0 + r;
    uint4 raw = make_uint4(0u, 0u, 0u, 0u);
    if (row < NE) {
      size_t idx = (size_t)row * 64 + k;
      if (MODE == 2) {
        float2 rp = ((const float2*)ef2)[row];
        float r0 = 1.0f / rp.x;
        float r1 = 1.0f / rp.y;
        float4 bA = *(const float4*)(eb + k), bB = *(const float4*)(eb + k + 4);
        float4 waA = *(const float4*)(ew + k), waB = *(const float4*)(ew + k + 4);
        float4 wbA = *(const float4*)(ew + 64 + k), wbB = *(const float4*)(ew + 64 + k + 4);
        float v[8];
        v[0] = bA.x + r0 * waA.x + r1 * wbA.x;
        v[1] = bA.y + r0 * waA.y + r1 * wbA.y;
        v[2] = bA.z + r0 * waA.z + r1 * wbA.z;
        v[3] = bA.w + r0 * waA.w + r1 * wbA.w;
        v[4] = bB.x + r0 * waB.x + r1 * wbB.x;
        v[5] = bB.y + r0 * waB.y + r1 * wbB.y;
        v[6] = bB.z + r0 * waB.z + r1 * wbB.z;
        v[7] = bB.w + r0 * waB.w + r1 * wbB.w;
        raw = pk8(v);
        if (EWRITE) *(uint4*)(e16 + idx) = raw;
      } else {
        raw = *(const uint4*)(e16 + idx);
        if (MODE == 1) {
          float v[8], pp[8];
          up8(raw, v);
          up8(*(const uint4*)(eh16 + idx), pp);
          float4 scA = *(const float4*)(bnp + 128 + k);
          float4 scB = *(const float4*)(bnp + 128 + k + 4);
          float4 shA = *(const float4*)(bnp + 192 + k);
          float4 shB = *(const float4*)(bnp + 192 + k + 4);
          float sc[8] = {scA.x, scA.y, scA.z, scA.w, scB.x, scB.y, scB.z, scB.w};
          float sh[8] = {shA.x, shA.y, shA.z, shA.w, shB.x, shB.y, shB.z, shB.w};
          #pragma unroll
          for (int j = 0; j < 8; ++j) v[j] += fmaxf(pp[j] * sc[j] + sh[j], 0.f);
          raw = pk8(v);
          if (EWRITE) *(uint4*)(e16 + idx) = raw;
        }
      }
    }
    int kk0 = k >> 1;        // multiple of 4
    esU[(kk0 + 0) * 256 + (r ^ SW(kk0 + 0))] = raw.x;
    esU[(kk0 + 1) * 256 + (r ^ SW(kk0 + 1))] = raw.y;
    esU[(kk0 + 2) * 256 + (r ^ SW(kk0 + 2))] = raw.z;
    esU[(kk0 + 3) * 256 + (r ^ SW(kk0 + 3))] = raw.w;
  }
  __syncthreads();
  int cg = t & 7, rg = t >> 3;   // rg 0..63 (4 rows each)
  int cb = cg * 8;
  float acc[4][8];
  #pragma unroll
  for (int r = 0; r < 4; ++r)
    #pragma unroll
    for (int j = 0; j < 8; ++j) acc[r][j] = 0.f;
  #pragma unroll 8
  for (int kk = 0; kk < 32; ++kk) {
    uint4 a4 = *(const uint4*)&esU[kk * 256 + ((rg * 4) ^ SW(kk))];
    uint4 wA = *(const uint4*)&cwU[kk * 64 + cb];
    uint4 wB = *(const uint4*)&cwU[kk * 64 + cb + 4];
    unsigned av[4] = {a4.x, a4.y, a4.z, a4.w};
    unsigned wv[8] = {wA.x, wA.y, wA.z, wA.w, wB.x, wB.y, wB.z, wB.w};
    #pragma unroll
    for (int r = 0; r < 4; ++r)
      #pragma unroll
      for (int j = 0; j < 8; ++j) acc[r][j] = dot2(av[r], wv[j], acc[r][j]);
  }
  float4 cb0 = *(const float4*)(Cb + cb);
  float4 cb1 = *(const float4*)(Cb + cb + 4);
  float cbv[8] = {cb0.x, cb0.y, cb0.z, cb0.w, cb1.x, cb1.y, cb1.z, cb1.w};
  float psum[8], psq[8];
  #pragma unroll
  for (int j = 0; j < 8; ++j) { psum[j] = 0.f; psq[j] = 0.f; }
  #pragma unroll
  for (int r = 0; r < 4; ++r) {
    int p = e0 + rg * 4 + r;
    if (p < NE) {
      int sN = srcp[p], dN = dstp[p];
      float dd[8], qq[8];
      up8(*(const uint4*)(Dh16 + (size_t)sN * 64 + cb), dd);
      up8(*(const uint4*)(Eh16 + (size_t)dN * 64 + cb), qq);
      float ev[8];
      #pragma unroll
      for (int j = 0; j < 8; ++j) {
        float v = acc[r][j] + cbv[j] + dd[j] + qq[j];
        ev[j] = v;
        if (ESTATS) { psum[j] += v; psq[j] += v * v; }
      }
      *(uint4*)(eh16 + (size_t)p * 64 + cb) = pk8(ev);
    }
  }
  if (ESTATS) {
    float* red = (float*)esU;   // 64*65 = 4160 floats < 8192
    __syncthreads();
    #pragma unroll
    for (int j = 0; j < 8; ++j) red[rg * 65 + cb + j] = psum[j];
    __syncthreads();
    if (t < 64) {
      float s = 0.f;
      #pragma unroll
      for (int i = 0; i < 64; ++i) s += red[i * 65 + t];
      atomAddD(stats + 128 + t, (double)s);
    }
    __syncthreads();
    #pragma unroll
    for (int j = 0; j < 8; ++j) red[rg * 65 + cb + j] = psq[j];
    __syncthreads();
    if (t < 64) {
      float q = 0.f;
      #pragma unroll
      for (int i = 0; i < 64; ++i) q += red[i * 65 + t];
      atomAddD(stats + 192 + t, (double)q);
    }
  }
}

// ---------------- aggregation: 128 nodes/block, 1024 threads, 1 col/thread ----------
// One node per 64-lane wave-group (uniform trip count). fp16 Ah read-modify-write.
// LAST==1 (layer 2): finalize also zeroes hg/counts for the readout.
template <int LAST>
__global__ __launch_bounds__(1024) void k_agg(const int* __restrict__ offs,
    const int* __restrict__ srcp, const __half* __restrict__ eh16,
    const __half* __restrict__ Bh16, __half* __restrict__ Ah16, double* __restrict__ stats,
    int* __restrict__ ctr,
    const float* __restrict__ hgam, const float* __restrict__ hbet,
    const float* __restrict__ egam, const float* __restrict__ ebet,
    float* __restrict__ bnp, float* __restrict__ hg) {
  int t = threadIdx.x;
  int c = t & 63;
  int g = t >> 6;   // 0..15
  float psum = 0.f, psq = 0.f;
  #pragma unroll 1
  for (int sub = 0; sub < 8; ++sub) {
    int n = blockIdx.x * 128 + g * 8 + sub;
    if (n < NN) {
      int i0 = offs[n], i1 = offs[n + 1];
      float num = 0.f, den = 0.f;
      int i = i0;
      #pragma unroll 1
      for (; i + 3 < i1; i += 4) {
        float x0 = __half2float(eh16[(size_t)(i + 0) * 64 + c]);
        float x1 = __half2float(eh16[(size_t)(i + 1) * 64 + c]);
        float x2 = __half2float(eh16[(size_t)(i + 2) * 64 + c]);
        float x3 = __half2float(eh16[(size_t)(i + 3) * 64 + c]);
        int s0 = srcp[i], s1 = srcp[i + 1], s2 = srcp[i + 2], s3 = srcp[i + 3];
        float b0 = __half2float(Bh16[(size_t)s0 * 64 + c]);
        float b1 = __half2float(Bh16[(size_t)s1 * 64 + c]);
        float b2 = __half2float(Bh16[(size_t)s2 * 64 + c]);
        float b3 = __half2float(Bh16[(size_t)s3 * 64 + c]);
        float g0 = 1.0f / (1.0f + __expf(-x0));
        float g1 = 1.0f / (1.0f + __expf(-x1));
        float g2 = 1.0f / (1.0f + __expf(-x2));
        float g3 = 1.0f / (1.0f + __expf(-x3));
        num += g0 * b0 + g1 * b1 + g2 * b2 + g3 * b3;
        den += g0 + g1 + g2 + g3;
      }
      #pragma unroll 1
      for (; i < i1; ++i) {
        float x0 = __half2float(eh16[(size_t)i * 64 + c]);
        int s0 = srcp[i];
        float b0 = __half2float(Bh16[(size_t)s0 * 64 + c]);
        float g0 = 1.0f / (1.0f + __expf(-x0));
        num += g0 * b0;
        den += g0;
      }
      size_t idx = (size_t)n * 64 + c;
      float v = __half2float(Ah16[idx]) + num / (den + 1e-6f);
      Ah16[idx] = __float2half(v);
      psum += v; psq += v * v;
    }
  }
  __shared__ float red[1024];
  red[t] = psum; __syncthreads();
  if (t < 64) {
    float s = 0.f;
    #pragma unroll
    for (int i = 0; i < 16; ++i) s += red[t + i * 64];
    atomAddD(stats + t, (double)s);
  }
  __syncthreads();
  red[t] = psq; __syncthreads();
  if (t < 64) {
    float q = 0.f;
    #pragma unroll
    for (int i = 0; i < 16; ++i) q += red[t + i * 64];
    atomAddD(stats + 64 + t, (double)q);
  }
  // ---- last-block finalize: compute BN scale/shift, reset stats ----
  __shared__ int lastFlag;
  __syncthreads();
  if (t == 0) {
    __threadfence();
    int old = atomAddI(ctr, 1);
    lastFlag = (old == (int)gridDim.x - 1);
  }
  __syncthreads();
  if (!lastFlag) return;
  if (t < 64) {
    double s = atomAddD(stats + t, 0.0);
    double q = atomAddD(stats + 64 + t, 0.0);
    double mu = s * (1.0 / NN);
    double var = q * (1.0 / NN) - mu * mu;
    float sc = hgam[t] / sqrtf((float)var + 1e-5f);
    bnp[t] = sc;
    bnp[64 + t] = hbet[t] - (float)mu * sc;
  } else if (t < 128) {
    int cc = t - 64;
    double s = atomAddD(stats + 128 + cc, 0.0);
    double q = atomAddD(stats + 192 + cc, 0.0);
    double mu = s * (1.0 / NE);
    double var = q * (1.0 / NE) - mu * mu;
    float sc = egam[cc] / sqrtf((float)var + 1e-5f);
    bnp[128 + cc] = sc;
    bnp[192 + cc] = ebet[cc] - (float)mu * sc;
  }
  __syncthreads();
  if (t < 256) atomicExch((unsigned long long*)&stats[t], 0ull);
  if (LAST) {
    for (int i = t; i < 1040; i += 1024) hg[i] = 0.f;
  }
}

// ---------------- readout with fused final h-residual (256 nodes/block) ------------
__global__ __launch_bounds__(256) void k_readout(const float* __restrict__ h,
    const __half* __restrict__ Ah16, const float* __restrict__ bnp,
    const int* __restrict__ gid, float* __restrict__ hg, float* __restrict__ counts) {
  int t = threadIdx.x;
  int c = t & 63;
  int ro = t >> 6;
  int nbase = blockIdx.x * 256;
  float sc = bnp[c], sh = bnp[64 + c];
  float sum = 0.f, cnt = 0.f;
  int curg = -1;
  #pragma unroll 1
  for (int i = 0; i < 64; ++i) {
    int n = nbase + ro + i * 4;
    if (n >= NN) break;
    int g = gid[n];
    if (g != curg) {
      if (curg >= 0) {
        atomAddF(&hg[curg * 64 + c], sum);
        if (c == 0) atomAddF(&counts[curg], cnt);
      }
      curg = g; sum = 0.f; cnt = 0.f;
    }
    size_t idx = (size_t)n * 64 + c;
    float av = __half2float(Ah16[idx]);
    sum += h[idx] + fmaxf(av * sc + sh, 0.f);
    cnt += 1.f;
  }
  if (curg >= 0) {
    atomAddF(&hg[curg * 64 + c], sum);
    if (c == 0) atomAddF(&counts[curg], cnt);
  }
}

// ---------------- final MLP (16 graphs), one block ----------------
__global__ __launch_bounds__(256) void k_mlp(const float* __restrict__ hg, const float* __restrict__ counts,
    const float* __restrict__ state,
    const float* __restrict__ w1, const float* __restrict__ b1,
    const float* __restrict__ w2, const float* __restrict__ b2,
    const float* __restrict__ w3, const float* __restrict__ b3,
    float* __restrict__ out) {
  __shared__ float x0[16][68];
  __shared__ float x1[16][256];
  __shared__ float x2[16][256];
  int t = threadIdx.x;
  for (int idx = t; idx < 16 * 68; idx += 256) {
    int g = idx / 68, c = idx % 68;
    x0[g][c] = (c < 64) ? hg[g * 64 + c] / counts[g] : state[g * 4 + (c - 64)];
  }
  __syncthreads();
  {
    float acc[16];
    float bb = b1[t];
    #pragma unroll
    for (int g = 0; g < 16; ++g) acc[g] = bb;
    for (int k = 0; k < 68; ++k) {
      float w = w1[k * 256 + t];
      #pragma unroll
      for (int g = 0; g < 16; ++g) acc[g] += x0[g][k] * w;
    }
    #pragma unroll
    for (int g = 0; g < 16; ++g) x1[g][t] = fmaxf(acc[g], 0.f);
  }
  __syncthreads();
  {
    float acc[16];
    float bb = b2[t];
    #pragma unroll
    for (int g = 0; g < 16; ++g) acc[g] = bb;
    for (int k = 0; k < 256; ++k) {
      float w = w2[k * 256 + t];
      #pragma unroll
      for (int g = 0; g < 16; ++g) acc[g] += x1[g][k] * w;
    }
    #pragma unroll
    for (int g = 0; g < 16; ++g) x2[g][t] = fmaxf(acc[g], 0.f);
  }
  __syncthreads();
  if (t < 32) {
    int g = t >> 1, o = t & 1;
    float acc = b3[o];
    for (int k = 0; k < 256; ++k) acc += x2[g][k] * w3[k * 2 + o];
    out[g * 2 + o] = tanhf(acc);
  }
}

extern "C" void kernel_launch(void* const* d_in, const int* in_sizes, int n_in,
                              void* d_out, int out_size, void* d_ws, size_t ws_size,
                              hipStream_t stream) {
  const float* state   = (const float*)d_in[0];
  const float* h_feat  = (const float*)d_in[1];
  const float* e_feat  = (const float*)d_in[2];
  const int*   src     = (const int*)d_in[3];
  const int*   dst     = (const int*)d_in[4];
  const int*   gid     = (const int*)d_in[5];
  const float* emb_h_w = (const float*)d_in[6];
  const float* emb_h_b = (const float*)d_in[7];
  const float* emb_e_w = (const float*)d_in[8];
  const float* emb_e_b = (const float*)d_in[9];
  const float* A_w = (const float*)d_in[10];
  const float* A_b = (const float*)d_in[11];
  const float* B_w = (const float*)d_in[12];
  const float* B_b = (const float*)d_in[13];
  const float* C_w = (const float*)d_in[14];
  const float* C_b = (const float*)d_in[15];
  const float* D_w = (const float*)d_in[16];
  const float* D_b = (const float*)d_in[17];
  const float* E_w = (const float*)d_in[18];
  const float* E_b = (const float*)d_in[19];
  const float* bn_h_g = (const float*)d_in[20];
  const float* bn_h_b = (const float*)d_in[21];
  const float* bn_e_g = (const float*)d_in[22];
  const float* bn_e_b = (const float*)d_in[23];
  const float* l1_w = (const float*)d_in[24];
  const float* l1_b = (const float*)d_in[25];
  const float* l2_w = (const float*)d_in[26];
  const float* l2_b = (const float*)d_in[27];
  const float* l3_w = (const float*)d_in[28];
  const float* l3_b = (const float*)d_in[29];

  float* wsp = (float*)d_ws;

  const size_t F_H = (size_t)NN * 64;       // fp32 node array (floats)
  const size_t F_H2 = (size_t)NN * 32;      // fp16 node array (float units)
  const size_t F_E2 = (size_t)NE * 32;      // fp16 edge array (float units)
  size_t off = 0;
  float*  h     = wsp + off; off += F_H;
  __half* Ah16  = (__half*)(wsp + off); off += F_H2;
  __half* e16   = (__half*)(wsp + off); off += F_E2;
  __half* eh16  = (__half*)(wsp + off); off += F_E2;
  float*  ef2   = wsp + off; off += (size_t)NE * 2;
  __half* Bh16  = (__half*)(wsp + off); off += F_H2;
  __half* Dh16  = (__half*)(wsp + off); off += F_H2;
  __half* Eh16  = (__half*)(wsp + off); off += F_H2;
  int* srcp    = (int*)(wsp + off); off += NE;
  int* dstp    = (int*)(wsp + off); off += NE;
  int* offs    = (int*)(wsp + off); off += NN + 4;
  int* degcur  = (int*)(wsp + off); off += NN + 4;   // deg/cursor + 3 ctrs + pad
  int* locx    = (int*)(wsp + off); off += NN;
  int* bsum    = (int*)(wsp + off); off += 256;
  double* stats = (double*)(wsp + off); off += 512;
  float* bnp    = wsp + off; off += 256;
  float* hg     = wsp + off; off += 1024;
  float* counts = hg + 1024; off += 16;
  const size_t need = off * sizeof(float);
  if (ws_size < need) return;
  int* ctr = degcur + NN;   // 3 layer counters

  const int NB = (NN + 255) / 256;   // 196 scan blocks

  // CSR build (zero also clears the 3 counters)
  k_zero<<<64, 256, 0, stream>>>((float4*)degcur, (NN + 4) / 4);
  k_deg<<<(NE + 255) / 256, 256, 0, stream>>>(dst, degcur);
  k_scanA<<<NB, 256, 0, stream>>>(degcur, locx, bsum);
  k_scanB<<<1, 256, 0, stream>>>(bsum, NB, stats);
  k_scanC<<<NB, 256, 0, stream>>>(locx, bsum, offs, degcur);
  k_scatter<<<(NE + 255) / 256, 256, 0, stream>>>(dst, src, e_feat, degcur, srcp, dstp, ef2);

  const int GN = (NN + 255) / 256;
  const int GE = (NE + 255) / 256;
  const int GA = (NN + 127) / 128;
  for (int l = 0; l < 3; ++l) {
    if (l == 0)
      k_node_gemm<2><<<GN, 512, 0, stream>>>(h, Ah16, bnp, h_feat, emb_h_w, emb_h_b,
          A_w, B_w, D_w, E_w, A_b, B_b, D_b, E_b, Ah16, Bh16, Dh16, Eh16);
    else
      k_node_gemm<1><<<GN, 512, 0, stream>>>(h, Ah16, bnp, h_feat, emb_h_w, emb_h_b,
          A_w + l * 4096, B_w + l * 4096, D_w + l * 4096, E_w + l * 4096,
          A_b + l * 64, B_b + l * 64, D_b + l * 64, E_b + l * 64,
          Ah16, Bh16, Dh16, Eh16);
    if (l == 0)
      k_edge_f<2, 1, 1><<<GE, 512, 0, stream>>>(e16, eh16, C_w, C_b,
          srcp, dstp, Dh16, Eh16, bnp, stats, ef2, emb_e_w, emb_e_b);
    else if (l == 1)
      k_edge_f<1, 1, 1><<<GE, 512, 0, stream>>>(e16, eh16, C_w + 4096, C_b + 64,
          srcp, dstp, Dh16, Eh16, bnp, stats, ef2, emb_e_w, emb_e_b);
    else
      k_edge_f<1, 0, 0><<<GE, 512, 0, stream>>>(e16, eh16, C_w + 8192, C_b + 128,
          srcp, dstp, Dh16, Eh16, bnp, stats, ef2, emb_e_w, emb_e_b);
    if (l < 2)
      k_agg<0><<<GA, 1024, 0, stream>>>(offs, srcp, eh16, Bh16, Ah16, stats, ctr + l,
          bn_h_g + l * 64, bn_h_b + l * 64, bn_e_g + l * 64, bn_e_b + l * 64, bnp, hg);
    else
      k_agg<1><<<GA, 1024, 0, stream>>>(offs, srcp, eh16, Bh16, Ah16, stats, ctr + l,
          bn_h_g + l * 64, bn_h_b + l * 64, bn_e_g + l * 64, bn_e_b + l * 64, bnp, hg);
  }
  k_readout<<<(NN + 255) / 256, 256, 0, stream>>>(h, Ah16, bnp, gid, hg, counts);
  k_mlp<<<1, 256, 0, stream>>>(hg, counts, state,
      l1_w, l1_b, l2_w, l2_b, l3_w, l3_b, (float*)d_out);
}